// Round 10
// baseline (593.477 us; speedup 1.0000x reference)
//
#include <hip/hip_runtime.h>
#include <hip/hip_cooperative_groups.h>

namespace cg = cooperative_groups;

#define N_NODES 100000
#define N_EDGES 1600000
#define D_FEAT  128
#define C_CLS   40
#define LN_EPS  1e-5f

#define RPB   256                         // rows per bucket
#define NBKT  ((N_NODES + RPB - 1) / RPB) // 391
#define BCAP  6144                        // padded slots/bucket (mean 4092, sigma~64)
#define TILE_E 4096                       // edges per bin tile
#define EBLK  ((N_EDGES + TILE_E - 1) / TILE_E)  // 391 == NBKT
#define EREG  20                          // register-staged edges per thread (5120 cap)

typedef __attribute__((ext_vector_type(8))) short short8;
typedef __attribute__((ext_vector_type(4))) float floatx4;

// ---------- bf16 pack/unpack (storage only; accumulate fp32) ----------
__device__ inline unsigned pack_bf2(float x, float y) {
    unsigned xi = __float_as_uint(x);
    unsigned yi = __float_as_uint(y);
    unsigned lo = (xi + 0x7fffu + ((xi >> 16) & 1u)) >> 16;
    unsigned hi = (yi + 0x7fffu + ((yi >> 16) & 1u)) & 0xffff0000u;
    return lo | hi;
}
__device__ inline float bf_lo(unsigned v) { return __uint_as_float(v << 16); }
__device__ inline float bf_hi(unsigned v) { return __uint_as_float(v & 0xffff0000u); }

// ==== cooperative build: conv + bin + refine (one kernel, 391 blocks) ====
__global__ __launch_bounds__(256) void build_k(const float* __restrict__ feat,
                                               unsigned* __restrict__ hb,
                                               const int* __restrict__ row,
                                               const int* __restrict__ col,
                                               int* __restrict__ bktsz,
                                               int* __restrict__ csr_tmp,
                                               int2* __restrict__ rowinfo,
                                               float* __restrict__ dinv,
                                               float* __restrict__ selfc,
                                               int2* __restrict__ csr) {
    cg::grid_group grid = cg::this_grid();
    int b = blockIdx.x, t = threadIdx.x;

    __shared__ int hist[NBKT];    // phase1: coarse hist; phase2: reused (256 rows)
    __shared__ int cbase[NBKT];   // phase1: chunk bases; phase2: psc scan buffer
    __shared__ float dl[RPB];

    // ---- phase 0: zero bktsz (block 0) + feat fp32 -> bf16 (grid-stride) ----
    if (b == 0) for (int i = t; i < NBKT; i += 256) bktsz[i] = 0;
    const float2* f2 = (const float2*)feat;
    for (int i = b * 256 + t; i < N_NODES * 64; i += EBLK * 256) {
        float2 v = f2[i];
        hb[i] = pack_bf2(v.x, v.y);
    }
    grid.sync();

    // ---- phase 1: bin tile b into coarse buckets ----
    for (int i = t; i < NBKT; i += 256) hist[i] = 0;
    __syncthreads();
    {
        int tile = b * TILE_E;
        int r[16], c[16], pos[16];
        #pragma unroll
        for (int k = 0; k < 16; k++) {
            int e = tile + k * 256 + t;
            if (e < N_EDGES) {
                r[k] = row[e]; c[k] = col[e];
                pos[k] = atomicAdd(&hist[r[k] / RPB], 1);
            } else r[k] = -1;
        }
        __syncthreads();
        for (int i = t; i < NBKT; i += 256) {
            int h = hist[i];
            cbase[i] = h ? atomicAdd(&bktsz[i], h) : 0;
        }
        __syncthreads();
        #pragma unroll
        for (int k = 0; k < 16; k++) {
            if (r[k] >= 0) {
                int bb = r[k] / RPB;
                int slot = cbase[bb] + pos[k];
                if (slot < BCAP)   // statistically impossible overflow guard
                    csr_tmp[bb * BCAP + slot] = ((r[k] & (RPB - 1)) << 17) | c[k];
            }
        }
    }
    grid.sync();

    // ---- phase 2: refine bucket b: fine hist + scan -> rowinfo/dinv/selfc ----
    int r0 = b * RPB;
    int nrows = min(RPB, N_NODES - r0);
    int cnt = bktsz[b];
    const int* base = csr_tmp + b * BCAP;
    int ecap = min(cnt, EREG * 256);
    int pk[EREG];
    if (t < 256) hist[t] = 0;          // reuse low 256 as fine hist
    __syncthreads();
    #pragma unroll
    for (int k = 0; k < EREG; k++) {
        int i = t + k * 256;
        pk[k] = (i < ecap) ? base[i] : -1;
        if (pk[k] >= 0) atomicAdd(&hist[pk[k] >> 17], 1);
    }
    for (int i = ecap + t; i < cnt; i += 256)       // never taken in practice
        atomicAdd(&hist[base[i] >> 17], 1);
    __syncthreads();
    int v = hist[t];
    cbase[t] = v;                      // reuse cbase as scan buffer
    __syncthreads();
    for (int off = 1; off < 256; off <<= 1) {
        int x = (t >= off) ? cbase[t - off] : 0;
        __syncthreads();
        cbase[t] += x;
        __syncthreads();
    }
    int start = b * BCAP + cbase[t] - v;   // exclusive prefix, bucket-local
    float d = rsqrtf((float)v + 1.0f);
    if (t < nrows) {
        rowinfo[r0 + t] = make_int2(start, start + v);
        dinv[r0 + t]  = d;
        selfc[r0 + t] = 0.5f + 0.5f * d * d;
    }
    __syncthreads();
    hist[t] = start;                   // write cursor
    dl[t]   = d;
    __syncthreads();
    grid.sync();                       // all dinv complete before scatter

    // ---- phase 3: scatter register-held edges to final CSR w/ full weight ----
    #pragma unroll
    for (int k = 0; k < EREG; k++) {
        if (pk[k] >= 0) {
            int lr = pk[k] >> 17;
            int c  = pk[k] & 0x1FFFF;
            int p = atomicAdd(&hist[lr], 1);
            float w = (0.5f * dl[lr]) * dinv[c];
            csr[p] = make_int2(c, __float_as_int(w));
        }
    }
    for (int i = ecap + t; i < cnt; i += 256) {     // never taken in practice
        int pkv = base[i];
        int lr = pkv >> 17;
        int c  = pkv & 0x1FFFF;
        int p = atomicAdd(&hist[lr], 1);
        float w = (0.5f * dl[lr]) * dinv[c];
        csr[p] = make_int2(c, __float_as_int(w));
    }
}

// ---------------- propagation: one wave per node, bf16 h, scalar edge loop
// (R8 version: measured 61.6 us / step, FETCH at compulsory floor)
__global__ __launch_bounds__(256) void prop_bf_k(const unsigned* __restrict__ hin,
                                                 unsigned* __restrict__ hout,
                                                 const int2* __restrict__ rowinfo,
                                                 const int2* __restrict__ csr,
                                                 const float* __restrict__ selfc) {
    int wave = threadIdx.x >> 6, lane = threadIdx.x & 63;
    int node = blockIdx.x * 4 + wave;     // N % 4 == 0
    unsigned hv = hin[node * 64 + lane];
    float sc = selfc[node];
    float ax = bf_lo(hv) * sc, ay = bf_hi(hv) * sc;
    int2 ri = rowinfo[node];
    int start = __builtin_amdgcn_readfirstlane(ri.x);
    int end   = __builtin_amdgcn_readfirstlane(ri.y);
    int j = start;
    int n8 = start + ((end - start) & ~7);
    for (; j < n8; j += 8) {
        int2 e0 = csr[j],     e1 = csr[j + 1], e2 = csr[j + 2], e3 = csr[j + 3];
        int2 e4 = csr[j + 4], e5 = csr[j + 5], e6 = csr[j + 6], e7 = csr[j + 7];
        unsigned v0 = hin[(unsigned)e0.x * 64 + lane];
        unsigned v1 = hin[(unsigned)e1.x * 64 + lane];
        unsigned v2 = hin[(unsigned)e2.x * 64 + lane];
        unsigned v3 = hin[(unsigned)e3.x * 64 + lane];
        unsigned v4 = hin[(unsigned)e4.x * 64 + lane];
        unsigned v5 = hin[(unsigned)e5.x * 64 + lane];
        unsigned v6 = hin[(unsigned)e6.x * 64 + lane];
        unsigned v7 = hin[(unsigned)e7.x * 64 + lane];
        float w0 = __int_as_float(e0.y), w1 = __int_as_float(e1.y);
        float w2 = __int_as_float(e2.y), w3 = __int_as_float(e3.y);
        float w4 = __int_as_float(e4.y), w5 = __int_as_float(e5.y);
        float w6 = __int_as_float(e6.y), w7 = __int_as_float(e7.y);
        ax += w0 * bf_lo(v0); ay += w0 * bf_hi(v0);
        ax += w1 * bf_lo(v1); ay += w1 * bf_hi(v1);
        ax += w2 * bf_lo(v2); ay += w2 * bf_hi(v2);
        ax += w3 * bf_lo(v3); ay += w3 * bf_hi(v3);
        ax += w4 * bf_lo(v4); ay += w4 * bf_hi(v4);
        ax += w5 * bf_lo(v5); ay += w5 * bf_hi(v5);
        ax += w6 * bf_lo(v6); ay += w6 * bf_hi(v6);
        ax += w7 * bf_lo(v7); ay += w7 * bf_hi(v7);
    }
    for (; j < end; ++j) {
        int2 e = csr[j];
        unsigned v = hin[(unsigned)e.x * 64 + lane];
        float w = __int_as_float(e.y);
        ax += w * bf_lo(v); ay += w * bf_hi(v);
    }
    hout[node * 64 + lane] = pack_bf2(ax, ay);
}

// ---- fused fc + LayerNorm via MFMA: one wave per 16-node tile ----
// W staged once per block in LDS as packed bf16 (stride 65 kills b128 conflicts)
__global__ __launch_bounds__(256) void fcln_mfma_k(const unsigned* __restrict__ h,
                                                   const float* __restrict__ W,
                                                   const float* __restrict__ b,
                                                   const float* __restrict__ gamma,
                                                   const float* __restrict__ beta,
                                                   float* __restrict__ out) {
    __shared__ unsigned Wp[48 * 65];           // 48 classes x 64 bf16-pairs (+pad)
    int t = threadIdx.x;
    for (int idx = t; idx < 40 * 64; idx += 256) {
        int c = idx >> 6, p = idx & 63;
        Wp[c * 65 + p] = pack_bf2(W[c * 128 + 2 * p], W[c * 128 + 2 * p + 1]);
    }
    for (int idx = t; idx < 8 * 64; idx += 256) {
        int c = 40 + (idx >> 6), p = idx & 63;
        Wp[c * 65 + p] = 0u;
    }
    __syncthreads();

    int wave = t >> 6, lane = t & 63;
    int m = lane & 15, quad = lane >> 4;
    int tile = blockIdx.x * 4 + wave;
    int node0 = tile * 16;                      // tiles = N/16, grid exact

    short8 bfrag[3][4];
    float bias[3], gam[3], bet[3];
    #pragma unroll
    for (int ct = 0; ct < 3; ct++) {
        int c = ct * 16 + m;
        bool ok = (c < C_CLS);
        bias[ct] = ok ? b[c] : 0.0f;
        gam[ct]  = ok ? gamma[c] : 0.0f;
        bet[ct]  = ok ? beta[c] : 0.0f;
        #pragma unroll
        for (int ks = 0; ks < 4; ks++) {
            uint4 braw = *(const uint4*)&Wp[c * 65 + ks * 16 + quad * 4];
            short8 bf;
            bf[0] = (short)(braw.x & 0xffff); bf[1] = (short)(braw.x >> 16);
            bf[2] = (short)(braw.y & 0xffff); bf[3] = (short)(braw.y >> 16);
            bf[4] = (short)(braw.z & 0xffff); bf[5] = (short)(braw.z >> 16);
            bf[6] = (short)(braw.w & 0xffff); bf[7] = (short)(braw.w >> 16);
            bfrag[ct][ks] = bf;
        }
    }

    floatx4 acc0 = {0.f,0.f,0.f,0.f}, acc1 = acc0, acc2 = acc0;
    #pragma unroll
    for (int ks = 0; ks < 4; ks++) {
        const uint4* ap = (const uint4*)&h[(node0 + m) * 64 + ks * 16 + quad * 4];
        uint4 araw = *ap;
        short8 afrag;
        afrag[0] = (short)(araw.x & 0xffff); afrag[1] = (short)(araw.x >> 16);
        afrag[2] = (short)(araw.y & 0xffff); afrag[3] = (short)(araw.y >> 16);
        afrag[4] = (short)(araw.z & 0xffff); afrag[5] = (short)(araw.z >> 16);
        afrag[6] = (short)(araw.w & 0xffff); afrag[7] = (short)(araw.w >> 16);
        acc0 = __builtin_amdgcn_mfma_f32_16x16x32_bf16(afrag, bfrag[0][ks], acc0, 0, 0, 0);
        acc1 = __builtin_amdgcn_mfma_f32_16x16x32_bf16(afrag, bfrag[1][ks], acc1, 0, 0, 0);
        acc2 = __builtin_amdgcn_mfma_f32_16x16x32_bf16(afrag, bfrag[2][ks], acc2, 0, 0, 0);
    }

    #pragma unroll
    for (int r = 0; r < 4; r++) { acc0[r] += bias[0]; acc1[r] += bias[1]; acc2[r] += bias[2]; }

    float s[4], ss[4];
    #pragma unroll
    for (int r = 0; r < 4; r++) {
        s[r]  = acc0[r] + acc1[r] + acc2[r];
        ss[r] = acc0[r]*acc0[r] + acc1[r]*acc1[r] + acc2[r]*acc2[r];
    }
    #pragma unroll
    for (int o = 1; o < 16; o <<= 1) {
        #pragma unroll
        for (int r = 0; r < 4; r++) {
            s[r]  += __shfl_xor(s[r], o);
            ss[r] += __shfl_xor(ss[r], o);
        }
    }

    #pragma unroll
    for (int r = 0; r < 4; r++) {
        int node = node0 + quad * 4 + r;
        float mean = s[r] * (1.0f / C_CLS);
        float var  = ss[r] * (1.0f / C_CLS) - mean * mean;
        float inv  = rsqrtf(var + LN_EPS);
        float* orow = out + (size_t)node * C_CLS;
        orow[m]      = (acc0[r] - mean) * inv * gam[0] + bet[0];
        orow[16 + m] = (acc1[r] - mean) * inv * gam[1] + bet[1];
        if (m < 8)
            orow[32 + m] = (acc2[r] - mean) * inv * gam[2] + bet[2];
    }
}

// ---------------- launch ----------------
extern "C" void kernel_launch(void* const* d_in, const int* in_sizes, int n_in,
                              void* d_out, int out_size, void* d_ws, size_t ws_size,
                              hipStream_t stream) {
    const float* feat  = (const float*)d_in[0];
    const int*   row   = (const int*)d_in[1];
    const int*   col   = (const int*)d_in[2];
    const float* W     = (const float*)d_in[3];
    const float* b     = (const float*)d_in[4];
    const float* gamma = (const float*)d_in[5];
    const float* beta  = (const float*)d_in[6];
    float* out = (float*)d_out;

    char* ws = (char*)d_ws;
    size_t off = 0;
    auto alloc = [&](size_t bytes) {
        size_t o = off;
        off = (off + bytes + 255) & ~(size_t)255;
        return o;
    };
    float*    dinv     = (float*)   (ws + alloc((size_t)N_NODES * 4));
    float*    selfc    = (float*)   (ws + alloc((size_t)N_NODES * 4));
    int2*     rowinfo  = (int2*)    (ws + alloc((size_t)N_NODES * 8));
    int*      bktsz    = (int*)     (ws + alloc((size_t)NBKT * 4));
    int*      csr_tmp  = (int*)     (ws + alloc((size_t)NBKT * BCAP * 4));
    int2*     csr      = (int2*)    (ws + alloc((size_t)NBKT * BCAP * 8));
    unsigned* h0       = (unsigned*)(ws + alloc((size_t)N_NODES * 64 * 4));
    unsigned* h1       = (unsigned*)(ws + alloc((size_t)N_NODES * 64 * 4));

    void* args[] = { (void*)&feat, (void*)&h0, (void*)&row, (void*)&col,
                     (void*)&bktsz, (void*)&csr_tmp, (void*)&rowinfo,
                     (void*)&dinv, (void*)&selfc, (void*)&csr };
    hipLaunchCooperativeKernel((void*)build_k, dim3(NBKT), dim3(256), args, 0, stream);

    int pgrid = N_NODES / 4;
    prop_bf_k<<<pgrid, 256, 0, stream>>>(h0, h1, rowinfo, csr, selfc);
    prop_bf_k<<<pgrid, 256, 0, stream>>>(h1, h0, rowinfo, csr, selfc);
    prop_bf_k<<<pgrid, 256, 0, stream>>>(h0, h1, rowinfo, csr, selfc);
    prop_bf_k<<<pgrid, 256, 0, stream>>>(h1, h0, rowinfo, csr, selfc);

    int tiles = N_NODES / 16;                       // 6250
    int fblocks = tiles / 4;                        // 1562.5 -> need ceil
    fblocks = (tiles + 3) / 4;                      // 1563
    fcln_mfma_k<<<fblocks, 256, 0, stream>>>(h0, W, b, gamma, beta, out);
}